// Round 7
// baseline (263.171 us; speedup 1.0000x reference)
//
#include <hip/hip_runtime.h>
#include <hip/hip_bf16.h>
#include <cstddef>

// ---------------------------------------------------------------------------
// WTConv2d on MI355X, round 7: counted-vmcnt software pipeline (T3/T4).
// 3-deep LDS staging buffers, raw s_barrier, s_waitcnt vmcnt(VM) -- the main
// loop never drains vmcnt to 0, so global_load_lds latency is hidden across
// two K-steps instead of stalling every step (rounds 4-6 all pinned at
// MfmaUtil ~20% from the __syncthreads vmcnt(0) drain).
//
// Xp layout (u16): [B][HP][kblk:8][g:4][WP][e:8], cin = kblk*32+g*8+e
// wT layout (u16): [tap:9][kblk:8][g:4][cout:256][e:8]
// y  layout (f32): [B][H][W][256] (NHWC)
// ---------------------------------------------------------------------------

typedef __attribute__((ext_vector_type(8))) short short8;   // 8 bf16
typedef __attribute__((ext_vector_type(4))) float f32x4;

static __device__ __forceinline__ unsigned short f2bf(float f) {
    __hip_bfloat16 h = __float2bfloat16(f);
    return *reinterpret_cast<unsigned short*>(&h);
}

static __device__ __forceinline__ void gload_lds16(const short* g, short* l) {
    __builtin_amdgcn_global_load_lds(
        (const __attribute__((address_space(1))) void*)g,
        (__attribute__((address_space(3))) void*)l, 16, 0, 0);
}

template <int VM> static __device__ __forceinline__ void wait_vmcnt() {
    if constexpr (VM == 3)      asm volatile("s_waitcnt vmcnt(3)" ::: "memory");
    else if constexpr (VM == 4) asm volatile("s_waitcnt vmcnt(4)" ::: "memory");
    else                        asm volatile("s_waitcnt vmcnt(0)" ::: "memory");
}

// ---- weight prep (all 3 levels in one launch): grid (288, 3) ----
__global__ __launch_bounds__(256) void prep_w_kernel(
    const float* __restrict__ wa, const float* __restrict__ wb,
    const float* __restrict__ wc,
    unsigned short* __restrict__ ta, unsigned short* __restrict__ tb,
    unsigned short* __restrict__ tc)
{
    const float* w = (blockIdx.y == 0) ? wa : (blockIdx.y == 1) ? wb : wc;
    unsigned short* wT = (blockIdx.y == 0) ? ta : (blockIdx.y == 1) ? tb : tc;
    int idx = blockIdx.x * 256 + threadIdx.x;   // ((tap*8+kb)*4+g)*256+co
    int co = idx & 255;
    int g = (idx >> 8) & 3;
    int kb = (idx >> 10) & 7;
    int tap = idx >> 13;
    int cin0 = kb * 32 + g * 8;
    unsigned short tmp[8];
#pragma unroll
    for (int e = 0; e < 8; ++e)
        tmp[e] = f2bf(w[((size_t)co * 256 + cin0 + e) * 9 + tap]);
    *(short8*)(wT + (size_t)idx * 8) = *(const short8*)tmp;
}

// ---- zero only the pad borders of the three Xp buffers (one launch) ----
__global__ __launch_bounds__(256) void border_zero_kernel(
    unsigned short* __restrict__ p0, unsigned short* __restrict__ p1,
    unsigned short* __restrict__ p2)
{
    constexpr int N0 = 49664, N1 = 25088, N2 = 12800;   // 16B border chunks
    int idx = blockIdx.x * 256 + threadIdx.x;
    unsigned short* base; int HP, WP, rel;
    if (idx < N0)           { base = p0; HP = 98; WP = 98; rel = idx; }
    else if (idx < N0 + N1) { base = p1; HP = 50; WP = 50; rel = idx - N0; }
    else if (idx < N0 + N1 + N2) { base = p2; HP = 26; WP = 26; rel = idx - N0 - N1; }
    else return;
    int nb = 64 * WP + (HP - 2) * 64;   // border chunks per batch
    int b = rel / nb, r = rel % nb;
    int row, kg, px;
    if (r < 64 * WP) {                  // full top/bottom rows
        int rowSel = r / (32 * WP), rr = r % (32 * WP);
        kg = rr / WP; px = rr % WP; row = rowSel ? (HP - 1) : 0;
    } else {                            // left/right columns
        int r2 = r - 64 * WP;
        row = 1 + (r2 >> 6);
        int r3 = r2 & 63;
        kg = r3 >> 1; px = (r3 & 1) ? (WP - 1) : 0;
    }
    size_t o = (((size_t)(b * HP + row) * 32 + kg) * WP + px) * 8;
    short8 z = {};
    *(short8*)(base + o) = z;
}

// ---- DWT level 0: x NCHW f32 [4][64][192][192] -> Xp0 (HP=98, WP=98) ----
__global__ __launch_bounds__(256) void dwt0_kernel(
    const float* __restrict__ x, unsigned short* __restrict__ Xp)
{
    __shared__ float lds[4 * 64 * 17];
    const int j0 = blockIdx.x * 16;
    const int i  = blockIdx.y;
    const int b  = blockIdx.z;
    const int tid = threadIdx.x;
    const int j = tid & 15;
    const int c4 = tid >> 4;
#pragma unroll
    for (int it = 0; it < 4; ++it) {
        int c = c4 + it * 16;
        const float* p = x + ((size_t)(b * 64 + c) * 192 + 2 * i) * 192 + 2 * (j0 + j);
        float2 top = *(const float2*)p;
        float2 bot = *(const float2*)(p + 192);
        float a = top.x, bb = top.y, cc = bot.x, dd = bot.y;
        const float s2 = 0.25f;
        lds[(0 * 64 + c) * 17 + j] = s2 * (a + bb + cc + dd);
        lds[(1 * 64 + c) * 17 + j] = s2 * (a + bb - cc - dd);
        lds[(2 * 64 + c) * 17 + j] = s2 * (a - bb + cc - dd);
        lds[(3 * 64 + c) * 17 + j] = s2 * (a - bb - cc + dd);
    }
    __syncthreads();
#pragma unroll
    for (int it = 0; it < 2; ++it) {
        int idx = it * 256 + tid;
        int jj = idx & 15;
        int g = (idx >> 4) & 3;
        int kb = idx >> 6;
        int sub = kb >> 1;
        int c0 = (kb & 1) * 32 + g * 8;
        unsigned short tmp[8];
#pragma unroll
        for (int e = 0; e < 8; ++e)
            tmp[e] = f2bf(lds[(sub * 64 + c0 + e) * 17 + jj]);
        size_t o = ((((size_t)(b * 98 + 1 + i) * 8 + kb) * 4 + g) * 98 + 1 + j0 + jj) * 8;
        *(short8*)(Xp + o) = *(const short8*)tmp;
    }
}

// ---- DWT mid: y NHWC f32 (ch<64 = ll) -> Xp next level ----
template <int H2, int JB>
__global__ __launch_bounds__(256) void dwt_mid_kernel(
    const float* __restrict__ in, unsigned short* __restrict__ Xp)
{
    constexpr int W2 = H2, Wi = 2 * W2, WPn = W2 + 2, HPn = H2 + 2;
    constexpr int LS = JB + 1;
    __shared__ float lds[4 * 64 * LS];
    const int j0 = blockIdx.x * JB;
    const int i = blockIdx.y;
    const int b = blockIdx.z;
    const int tid = threadIdx.x;
    const int c = tid & 63;
    const int jq = tid >> 6;
#pragma unroll
    for (int it = 0; it < JB / 4; ++it) {
        int jl = jq + it * 4;
        int j = j0 + jl;
        const float* p = in + ((size_t)(b * 2 * H2 + 2 * i) * Wi + 2 * j) * 256 + c;
        float a  = p[0];
        float bb = p[256];
        float cc = p[(size_t)Wi * 256];
        float dd = p[(size_t)Wi * 256 + 256];
        const float s2 = 0.25f;
        lds[(0 * 64 + c) * LS + jl] = s2 * (a + bb + cc + dd);
        lds[(1 * 64 + c) * LS + jl] = s2 * (a + bb - cc - dd);
        lds[(2 * 64 + c) * LS + jl] = s2 * (a - bb + cc - dd);
        lds[(3 * 64 + c) * LS + jl] = s2 * (a - bb - cc + dd);
    }
    __syncthreads();
    constexpr int CH = 8 * 4 * JB;
#pragma unroll
    for (int it = 0; it < (CH + 255) / 256; ++it) {
        int idx = it * 256 + tid;
        if (idx < CH) {
            int jj = idx % JB;
            int g = (idx / JB) & 3;
            int kb = idx / (JB * 4);
            int sub = kb >> 1;
            int c0 = (kb & 1) * 32 + g * 8;
            unsigned short tmp[8];
#pragma unroll
            for (int e = 0; e < 8; ++e)
                tmp[e] = f2bf(lds[(sub * 64 + c0 + e) * LS + jj]);
            size_t o = ((((size_t)(b * HPn + 1 + i) * 8 + kb) * 4 + g) * WPn + 1 + j0 + jj) * 8;
            *(short8*)(Xp + o) = *(const short8*)tmp;
        }
    }
}

// ---- conv: counted-vmcnt pipelined LDS-staged implicit GEMM ----
// Block: MT couts x (PR x PC) pixels, WM x WN waves. K = 9 taps x 8 kb = 72
// steps. Step k: stage batch k+2 (global_load_lds), ds_read batch k, MFMA,
// s_waitcnt vmcnt(VM) [batch k+1 landed], s_barrier.
template <int HP, int WP, int MT, int PR, int PC, int WM, int WN, int XCHUNK>
__global__ __launch_bounds__(WM * WN * 64) void conv_lds_kernel(
    const short* __restrict__ Xp, const short* __restrict__ Wt,
    float* __restrict__ Y)
{
    constexpr int NPX = PR * PC;
    constexpr int NWAVE = WM * WN;
    constexpr int MFR = MT / (16 * WM);
    constexpr int NFR = NPX / (16 * WN);
    constexpr int H = HP - 2, W = WP - 2;
    constexpr int rowT = H / PR, colT = W / PC;
    constexpr size_t S_r = (size_t)256 * WP;
    constexpr size_t S_kb = (size_t)32 * WP;
    constexpr size_t S_g = (size_t)8 * WP;
    constexpr int TA = MT / 16;      // A stage insts per step
    constexpr int TB = NPX / 16;     // B stage insts per step
    constexpr int VM = (TA + TB) / NWAVE;   // per-wave loads per batch
    constexpr int NSTEP = 72;

    __shared__ __align__(16) short lsA[3][MT * 32];
    __shared__ __align__(16) short lsB[3][NPX * 32];

    int bid = blockIdx.x;
    if (XCHUNK > 0) bid = (bid & 7) * XCHUNK + (bid >> 3);
    const int tx = bid % colT; bid /= colT;
    const int ty = bid % rowT; bid /= rowT;
    const int b = bid;
    const int gy0 = ty * PR;
    const int gx0 = tx * PC;
    const int cb = blockIdx.y * MT;

    const int lane = threadIdx.x & 63;
    const int wid = threadIdx.x >> 6;
    const int wm = wid / WN, wn = wid % WN;

    // staging per-lane constants (dest-linear, inverse-swizzled source)
    const int l4 = lane >> 2;                    // 0..15
    const int gs = (lane & 3) ^ (l4 & 3);        // cin-group this lane fetches
    const size_t aLane = (size_t)gs * 2048 + (size_t)(cb + l4) * 8;
    const int r0 = l4 / PC, c0 = l4 % PC;
    const size_t bLane = (size_t)(b * HP + gy0 + r0) * S_r + (size_t)gs * S_g
                       + (size_t)(gx0 + c0) * 8;

    // compute-phase per-lane constants
    const int n15 = lane & 15, gq = lane >> 4;
    const int slot = gq ^ (n15 & 3);
    const int aRd = (wm * 16 * MFR + n15) * 32 + slot * 8;
    const int bRd = (wn * 16 * NFR + n15) * 32 + slot * 8;

    f32x4 acc[MFR][NFR] = {};

    auto stage = [&](int kk, short* dA, short* dB) {
        kk = (kk >= NSTEP) ? (NSTEP - 1) : kk;   // tail: redundant reload
        const int sS = kk >> 3, kbS = kk & 7;
        const int kyS = sS / 3, kxS = sS - 3 * kyS;
#pragma unroll
        for (int t = 0; t < TA; ++t)
            if ((t & (NWAVE - 1)) == wid)
                gload_lds16(Wt + (size_t)sS * 65536 + (size_t)kbS * 8192
                                + aLane + t * 128,
                            dA + t * 512);
#pragma unroll
        for (int j = 0; j < TB; ++j)
            if (((TA + j) & (NWAVE - 1)) == wid)
                gload_lds16(Xp + bLane + (size_t)((16 * j) / PC + kyS) * S_r
                                + (size_t)kbS * S_kb + kxS * 8,
                            dB + j * 512);
    };

    auto step = [&](int k, const short* rA, const short* rB,
                    short* wA, short* wB) {
        stage(k + 2, wA, wB);
        short8 av[MFR], bv[NFR];
#pragma unroll
        for (int m = 0; m < MFR; ++m)
            av[m] = *(const short8*)&rA[aRd + m * 512];
#pragma unroll
        for (int n = 0; n < NFR; ++n)
            bv[n] = *(const short8*)&rB[bRd + n * 512];
        __builtin_amdgcn_s_setprio(1);
#pragma unroll
        for (int m = 0; m < MFR; ++m)
#pragma unroll
            for (int n = 0; n < NFR; ++n)
                acc[m][n] = __builtin_amdgcn_mfma_f32_16x16x32_bf16(
                    av[m], bv[n], acc[m][n], 0, 0, 0);
        __builtin_amdgcn_s_setprio(0);
        wait_vmcnt<VM>();                 // batch k+1 landed; k+2 in flight
        __builtin_amdgcn_s_barrier();
    };

    // prologue: batches 0,1 in flight; wait batch 0 only
    stage(0, &lsA[0][0], &lsB[0][0]);
    stage(1, &lsA[1][0], &lsB[1][0]);
    wait_vmcnt<VM>();
    __builtin_amdgcn_s_barrier();

#pragma unroll 1
    for (int k = 0; k < NSTEP; k += 3) {
        step(k,     &lsA[0][0], &lsB[0][0], &lsA[2][0], &lsB[2][0]);
        step(k + 1, &lsA[1][0], &lsB[1][0], &lsA[0][0], &lsB[0][0]);
        step(k + 2, &lsA[2][0], &lsB[2][0], &lsA[1][0], &lsB[1][0]);
    }
    asm volatile("s_waitcnt vmcnt(0)" ::: "memory");  // drain tail DMAs

    // D: col(lane&15)=pixel, row=(lane>>4)*4+reg=cout-within-16
#pragma unroll
    for (int m = 0; m < MFR; ++m)
#pragma unroll
        for (int n = 0; n < NFR; ++n) {
            int cout = cb + wm * 16 * MFR + m * 16 + gq * 4;
            int pxl = wn * 16 * NFR + n * 16 + n15;
            int r = pxl / PC, c = pxl % PC;
            float* op = Y + ((size_t)(b * H + gy0 + r) * W + gx0 + c) * 256 + cout;
            *(f32x4*)op = acc[m][n];
        }
}

// ---- IDWT mid: ll (NHWC, llStride ch) + hi (NHWC 256ch) -> out 64ch NHWC ----
template <int H2>
__global__ __launch_bounds__(256) void idwt_mid_kernel(
    const float* __restrict__ ll, int llStride,
    const float* __restrict__ hi, float* __restrict__ out)
{
    constexpr int W2 = H2;
    const int c = threadIdx.x & 63;
    const int jj = threadIdx.x >> 6;
    const int j = blockIdx.x * 4 + jj;
    const int i = blockIdx.y;
    const int b = blockIdx.z;

    size_t pix = (size_t)(b * H2 + i) * W2 + j;
    float vll = ll[pix * llStride + c];
    const float* hp = hi + pix * 256;
    float vlh = hp[64 + c];
    float vhl = hp[128 + c];
    float vhh = hp[192 + c];
    float a  = vll + vlh + vhl + vhh;
    float b2 = vll + vlh - vhl - vhh;
    float c2 = vll - vlh + vhl - vhh;
    float d2 = vll - vlh - vhl + vhh;
    float* op = out + ((size_t)(b * 2 * H2 + 2 * i) * (2 * W2) + 2 * j) * 64 + c;
    op[0] = a;
    op[64] = b2;
    op[(size_t)(2 * W2) * 64] = c2;
    op[(size_t)(2 * W2) * 64 + 64] = d2;
}

// ---- final IDWT: ll0u [4][96][96][64] + y0 highs + bias -> out NCHW f32 ----
__global__ __launch_bounds__(256) void idwt_final_kernel(
    const float* __restrict__ ll, const float* __restrict__ hi,
    const float* __restrict__ bias, float* __restrict__ out)
{
    __shared__ float lds[16 * 324];
    const int tt = blockIdx.x;               // 12x12 tiles
    const int tyi = tt / 12, txi = tt % 12;
    const int y0 = tyi * 8, x0 = txi * 8;
    const int cg = blockIdx.y;               // 0..3
    const int b = blockIdx.z;
    const int tid = threadIdx.x;

#pragma unroll
    for (int rep = 0; rep < 4; ++rep) {
        int idx = rep * 256 + tid;
        int c16 = idx & 15;
        int px = idx >> 4;                   // 0..63
        int pi = px >> 3, pj = px & 7;
        int c = cg * 16 + c16;
        size_t pix = (size_t)(b * 96 + y0 + pi) * 96 + x0 + pj;
        float vll = ll[pix * 64 + c];
        const float* hp = hi + pix * 256;
        float vlh = hp[64 + c];
        float vhl = hp[128 + c];
        float vhh = hp[192 + c];
        float bv = bias[c];
        float a  = vll + vlh + vhl + vhh + bv;
        float b2 = vll + vlh - vhl - vhh + bv;
        float c2 = vll - vlh + vhl - vhh + bv;
        float d2 = vll - vlh - vhl + vhh + bv;
        float* l = lds + c16 * 324 + (2 * pi) * 20 + 2 * pj;
        l[0] = a; l[1] = b2;
        l[20] = c2; l[21] = d2;
    }
    __syncthreads();

    const int c16 = tid >> 4;
    const int yy = tid & 15;
    const float* l = lds + c16 * 324 + yy * 20;
    float* op = out + ((size_t)(b * 64 + cg * 16 + c16) * 192 + tyi * 16 + yy) * 192 + txi * 16;
#pragma unroll
    for (int q = 0; q < 4; ++q)
        *(f32x4*)(op + 4 * q) = *(const f32x4*)(l + 4 * q);
}

extern "C" void kernel_launch(void* const* d_in, const int* in_sizes, int n_in,
                              void* d_out, int out_size, void* d_ws, size_t ws_size,
                              hipStream_t stream)
{
    const float* x    = (const float*)d_in[0];
    const float* w0   = (const float*)d_in[1];
    const float* w1   = (const float*)d_in[2];
    const float* w2   = (const float*)d_in[3];
    const float* bias = (const float*)d_in[4];
    float* out = (float*)d_out;

    char* ws = (char*)d_ws;
    unsigned short* wT0 = (unsigned short*)(ws + 0);          // 1,179,648 B
    unsigned short* wT1 = (unsigned short*)(ws + 1179648);
    unsigned short* wT2 = (unsigned short*)(ws + 2359296);
    unsigned short* Xp0 = (unsigned short*)(ws + 3538944);    // 19,668,992 B
    unsigned short* Xp1 = (unsigned short*)(ws + 23207936);   //  5,120,000 B
    unsigned short* Xp2 = (unsigned short*)(ws + 28327936);   //  1,384,448 B
    float* y0 = (float*)(ws + 29712384);                      // 37,748,736 B
    float* y1 = (float*)(ws + 67461120);                      //  9,437,184 B
    float* y2 = (float*)(ws + 76898304);                      //  2,359,296 B
    float* ll1u = (float*)Xp1;   // alias: Xp1 dead after conv1
    float* ll0u = (float*)Xp0;   // alias: Xp0 dead after conv0

    border_zero_kernel<<<342, 256, 0, stream>>>(Xp0, Xp1, Xp2);
    prep_w_kernel<<<dim3(288, 3), 256, 0, stream>>>(w0, w1, w2, wT0, wT1, wT2);

    dwt0_kernel<<<dim3(6, 96, 4), 256, 0, stream>>>(x, Xp0);
    // 96x96: 128co x 128px blocks; pixel tiles 4*12*6 = 288 (=8*36), 2 cout slices
    conv_lds_kernel<98, 98, 128, 8, 16, 2, 2, 36><<<dim3(288, 2), 256, 0, stream>>>(
        (const short*)Xp0, (const short*)wT0, y0);

    dwt_mid_kernel<48, 16><<<dim3(3, 48, 4), 256, 0, stream>>>(y0, Xp1);
    // 48x48: 128co x 128px; pixel tiles 4*6*3 = 72 (=8*9), 2 cout slices
    conv_lds_kernel<50, 50, 128, 8, 16, 2, 2, 9><<<dim3(72, 2), 256, 0, stream>>>(
        (const short*)Xp1, (const short*)wT1, y1);

    dwt_mid_kernel<24, 12><<<dim3(2, 24, 4), 256, 0, stream>>>(y1, Xp2);
    // 24x24: 128co x 64px; pixel tiles 4*3*3 = 36, 2 cout slices
    conv_lds_kernel<26, 26, 128, 8, 8, 2, 2, 0><<<dim3(36, 2), 256, 0, stream>>>(
        (const short*)Xp2, (const short*)wT2, y2);

    idwt_mid_kernel<24><<<dim3(6, 24, 4), 256, 0, stream>>>(y2, 256, y2, ll1u);
    idwt_mid_kernel<48><<<dim3(12, 48, 4), 256, 0, stream>>>(ll1u, 64, y1, ll0u);
    idwt_final_kernel<<<dim3(144, 4, 4), 256, 0, stream>>>(ll0u, y0, bias, out);
}

// Round 8
// 220.450 us; speedup vs baseline: 1.1938x; 1.1938x over previous
//
#include <hip/hip_runtime.h>
#include <hip/hip_bf16.h>
#include <cstddef>

// ---------------------------------------------------------------------------
// WTConv2d on MI355X, round 8: round-6 conv structure (2-buf LDS staging,
// __syncthreads per K-step) + K-split across grid.z (kb 0-3 / 4-7) to double
// block co-residency (2.25 -> 4.5 blocks/CU; m102: MfmaUtil tracks blocks/CU
// in this structure). z=1 writes partial f32 buffers; adds fused into the
// DWT/IDWT consumers. Falls back to unsplit if ws_size too small.
//
// Xp layout (u16): [B][HP][kblk:8][g:4][WP][e:8], cin = kblk*32+g*8+e
// wT layout (u16): [tap:9][kblk:8][g:4][cout:256][e:8]
// y  layout (f32): [B][H][W][256] (NHWC)
// ---------------------------------------------------------------------------

typedef __attribute__((ext_vector_type(8))) short short8;   // 8 bf16
typedef __attribute__((ext_vector_type(4))) float f32x4;

static __device__ __forceinline__ unsigned short f2bf(float f) {
    __hip_bfloat16 h = __float2bfloat16(f);
    return *reinterpret_cast<unsigned short*>(&h);
}

static __device__ __forceinline__ void gload_lds16(const short* g, short* l) {
    __builtin_amdgcn_global_load_lds(
        (const __attribute__((address_space(1))) void*)g,
        (__attribute__((address_space(3))) void*)l, 16, 0, 0);
}

// ---- weight prep (all 3 levels in one launch): grid (288, 3) ----
__global__ __launch_bounds__(256) void prep_w_kernel(
    const float* __restrict__ wa, const float* __restrict__ wb,
    const float* __restrict__ wc,
    unsigned short* __restrict__ ta, unsigned short* __restrict__ tb,
    unsigned short* __restrict__ tc)
{
    const float* w = (blockIdx.y == 0) ? wa : (blockIdx.y == 1) ? wb : wc;
    unsigned short* wT = (blockIdx.y == 0) ? ta : (blockIdx.y == 1) ? tb : tc;
    int idx = blockIdx.x * 256 + threadIdx.x;   // ((tap*8+kb)*4+g)*256+co
    int co = idx & 255;
    int g = (idx >> 8) & 3;
    int kb = (idx >> 10) & 7;
    int tap = idx >> 13;
    int cin0 = kb * 32 + g * 8;
    unsigned short tmp[8];
#pragma unroll
    for (int e = 0; e < 8; ++e)
        tmp[e] = f2bf(w[((size_t)co * 256 + cin0 + e) * 9 + tap]);
    *(short8*)(wT + (size_t)idx * 8) = *(const short8*)tmp;
}

// ---- zero only the pad borders of the three Xp buffers (one launch) ----
__global__ __launch_bounds__(256) void border_zero_kernel(
    unsigned short* __restrict__ p0, unsigned short* __restrict__ p1,
    unsigned short* __restrict__ p2)
{
    constexpr int N0 = 49664, N1 = 25088, N2 = 12800;   // 16B border chunks
    int idx = blockIdx.x * 256 + threadIdx.x;
    unsigned short* base; int HP, WP, rel;
    if (idx < N0)           { base = p0; HP = 98; WP = 98; rel = idx; }
    else if (idx < N0 + N1) { base = p1; HP = 50; WP = 50; rel = idx - N0; }
    else if (idx < N0 + N1 + N2) { base = p2; HP = 26; WP = 26; rel = idx - N0 - N1; }
    else return;
    int nb = 64 * WP + (HP - 2) * 64;   // border chunks per batch
    int b = rel / nb, r = rel % nb;
    int row, kg, px;
    if (r < 64 * WP) {                  // full top/bottom rows
        int rowSel = r / (32 * WP), rr = r % (32 * WP);
        kg = rr / WP; px = rr % WP; row = rowSel ? (HP - 1) : 0;
    } else {                            // left/right columns
        int r2 = r - 64 * WP;
        row = 1 + (r2 >> 6);
        int r3 = r2 & 63;
        kg = r3 >> 1; px = (r3 & 1) ? (WP - 1) : 0;
    }
    size_t o = (((size_t)(b * HP + row) * 32 + kg) * WP + px) * 8;
    short8 z = {};
    *(short8*)(base + o) = z;
}

// ---- DWT level 0: x NCHW f32 [4][64][192][192] -> Xp0 (HP=98, WP=98) ----
__global__ __launch_bounds__(256) void dwt0_kernel(
    const float* __restrict__ x, unsigned short* __restrict__ Xp)
{
    __shared__ float lds[4 * 64 * 17];
    const int j0 = blockIdx.x * 16;
    const int i  = blockIdx.y;
    const int b  = blockIdx.z;
    const int tid = threadIdx.x;
    const int j = tid & 15;
    const int c4 = tid >> 4;
#pragma unroll
    for (int it = 0; it < 4; ++it) {
        int c = c4 + it * 16;
        const float* p = x + ((size_t)(b * 64 + c) * 192 + 2 * i) * 192 + 2 * (j0 + j);
        float2 top = *(const float2*)p;
        float2 bot = *(const float2*)(p + 192);
        float a = top.x, bb = top.y, cc = bot.x, dd = bot.y;
        const float s2 = 0.25f;
        lds[(0 * 64 + c) * 17 + j] = s2 * (a + bb + cc + dd);
        lds[(1 * 64 + c) * 17 + j] = s2 * (a + bb - cc - dd);
        lds[(2 * 64 + c) * 17 + j] = s2 * (a - bb + cc - dd);
        lds[(3 * 64 + c) * 17 + j] = s2 * (a - bb - cc + dd);
    }
    __syncthreads();
#pragma unroll
    for (int it = 0; it < 2; ++it) {
        int idx = it * 256 + tid;
        int jj = idx & 15;
        int g = (idx >> 4) & 3;
        int kb = idx >> 6;
        int sub = kb >> 1;
        int c0 = (kb & 1) * 32 + g * 8;
        unsigned short tmp[8];
#pragma unroll
        for (int e = 0; e < 8; ++e)
            tmp[e] = f2bf(lds[(sub * 64 + c0 + e) * 17 + jj]);
        size_t o = ((((size_t)(b * 98 + 1 + i) * 8 + kb) * 4 + g) * 98 + 1 + j0 + jj) * 8;
        *(short8*)(Xp + o) = *(const short8*)tmp;
    }
}

// ---- DWT mid: y NHWC f32 (ch<64 = ll, + optional partial) -> Xp next ----
template <int H2, int JB>
__global__ __launch_bounds__(256) void dwt_mid_kernel(
    const float* __restrict__ in, const float* __restrict__ inB,
    unsigned short* __restrict__ Xp)
{
    constexpr int W2 = H2, Wi = 2 * W2, WPn = W2 + 2, HPn = H2 + 2;
    constexpr int LS = JB + 1;
    __shared__ float lds[4 * 64 * LS];
    const int j0 = blockIdx.x * JB;
    const int i = blockIdx.y;
    const int b = blockIdx.z;
    const int tid = threadIdx.x;
    const int c = tid & 63;
    const int jq = tid >> 6;
#pragma unroll
    for (int it = 0; it < JB / 4; ++it) {
        int jl = jq + it * 4;
        int j = j0 + jl;
        size_t off = ((size_t)(b * 2 * H2 + 2 * i) * Wi + 2 * j) * 256 + c;
        const float* p = in + off;
        float a  = p[0];
        float bb = p[256];
        float cc = p[(size_t)Wi * 256];
        float dd = p[(size_t)Wi * 256 + 256];
        if (inB) {
            const float* q = inB + off;
            a  += q[0];
            bb += q[256];
            cc += q[(size_t)Wi * 256];
            dd += q[(size_t)Wi * 256 + 256];
        }
        const float s2 = 0.25f;
        lds[(0 * 64 + c) * LS + jl] = s2 * (a + bb + cc + dd);
        lds[(1 * 64 + c) * LS + jl] = s2 * (a + bb - cc - dd);
        lds[(2 * 64 + c) * LS + jl] = s2 * (a - bb + cc - dd);
        lds[(3 * 64 + c) * LS + jl] = s2 * (a - bb - cc + dd);
    }
    __syncthreads();
    constexpr int CH = 8 * 4 * JB;
#pragma unroll
    for (int it = 0; it < (CH + 255) / 256; ++it) {
        int idx = it * 256 + tid;
        if (idx < CH) {
            int jj = idx % JB;
            int g = (idx / JB) & 3;
            int kb = idx / (JB * 4);
            int sub = kb >> 1;
            int c0 = (kb & 1) * 32 + g * 8;
            unsigned short tmp[8];
#pragma unroll
            for (int e = 0; e < 8; ++e)
                tmp[e] = f2bf(lds[(sub * 64 + c0 + e) * LS + jj]);
            size_t o = ((((size_t)(b * HPn + 1 + i) * 8 + kb) * 4 + g) * WPn + 1 + j0 + jj) * 8;
            *(short8*)(Xp + o) = *(const short8*)tmp;
        }
    }
}

// ---- conv: LDS-staged implicit GEMM, optional K-split over grid.z ----
// Block: MT couts x (PR x PC) pixels, WM x WN waves. K-steps = 9 taps x KB
// cin-blocks (KB = 8/KSPLIT). Per step: stage next (global_load_lds),
// ds_read_b128 current, MFMA, __syncthreads.
template <int HP, int WP, int MT, int PR, int PC, int WM, int WN, int XCHUNK,
          int KSPLIT>
__global__ __launch_bounds__(WM * WN * 64) void conv_lds_kernel(
    const short* __restrict__ Xp, const short* __restrict__ Wt,
    float* __restrict__ Y0, float* __restrict__ Y1)
{
    constexpr int NPX = PR * PC;
    constexpr int NWAVE = WM * WN;
    constexpr int MFR = MT / (16 * WM);
    constexpr int NFR = NPX / (16 * WN);
    constexpr int H = HP - 2, W = WP - 2;
    constexpr int rowT = H / PR, colT = W / PC;
    constexpr size_t S_r = (size_t)256 * WP;
    constexpr size_t S_kb = (size_t)32 * WP;
    constexpr size_t S_g = (size_t)8 * WP;
    constexpr int TA = MT / 16;      // A stage insts per step
    constexpr int TB = NPX / 16;     // B stage insts per step
    constexpr int KB = 8 / KSPLIT;   // cin-blocks per z-slice
    constexpr int STOT = 9 * KB;

    __shared__ __align__(16) short lsA[2][MT * 32];
    __shared__ __align__(16) short lsB[2][NPX * 32];

    int bid = blockIdx.x;
    if (XCHUNK > 0) bid = (bid & 7) * XCHUNK + (bid >> 3);
    const int tx = bid % colT; bid /= colT;
    const int ty = bid % rowT; bid /= rowT;
    const int b = bid;
    const int gy0 = ty * PR;
    const int gx0 = tx * PC;
    const int cb = blockIdx.y * MT;
    const int kz = (KSPLIT == 2) ? blockIdx.z : 0;
    const int kbBase = kz * KB;
    float* Y = (kz == 0) ? Y0 : Y1;

    const int lane = threadIdx.x & 63;
    const int wid = threadIdx.x >> 6;
    const int wm = wid / WN, wn = wid % WN;

    // staging per-lane constants (dest-linear, inverse-swizzled source)
    const int l4 = lane >> 2;                    // 0..15
    const int gs = (lane & 3) ^ (l4 & 3);        // cin-group this lane fetches
    const size_t aLane = (size_t)gs * 2048 + (size_t)(cb + l4) * 8;
    const int r0 = l4 / PC, c0 = l4 % PC;
    const size_t bLane = (size_t)(b * HP + gy0 + r0) * S_r + (size_t)gs * S_g
                       + (size_t)(gx0 + c0) * 8;

    // compute-phase per-lane constants
    const int n15 = lane & 15, gq = lane >> 4;
    const int slot = gq ^ (n15 & 3);
    const int aRd = (wm * 16 * MFR + n15) * 32 + slot * 8;
    const int bRd = (wn * 16 * NFR + n15) * 32 + slot * 8;

    f32x4 acc[MFR][NFR] = {};

    auto stage = [&](int kk, short* dA, short* dB) {
        kk = (kk >= STOT) ? (STOT - 1) : kk;   // tail: redundant reload
        const int sS = kk / KB;
        const int kbS = kbBase + kk % KB;
        const int kyS = sS / 3, kxS = sS - 3 * kyS;
#pragma unroll
        for (int t = 0; t < TA; ++t)
            if ((t & (NWAVE - 1)) == wid)
                gload_lds16(Wt + (size_t)sS * 65536 + (size_t)kbS * 8192
                                + aLane + t * 128,
                            dA + t * 512);
#pragma unroll
        for (int j = 0; j < TB; ++j)
            if (((TA + j) & (NWAVE - 1)) == wid)
                gload_lds16(Xp + bLane + (size_t)((16 * j) / PC + kyS) * S_r
                                + (size_t)kbS * S_kb + kxS * 8,
                            dB + j * 512);
    };

    stage(0, &lsA[0][0], &lsB[0][0]);
    __syncthreads();

#pragma unroll 1
    for (int s = 0; s < 9; ++s) {
#pragma unroll
        for (int kb = 0; kb < KB; ++kb) {
            const int cur = kb & 1;          // compile-time within unroll
            const int nb = cur ^ 1;
            const int k = s * KB + kb;

            stage(k + 1, &lsA[nb][0], &lsB[nb][0]);

            short8 av[MFR], bv[NFR];
#pragma unroll
            for (int m = 0; m < MFR; ++m)
                av[m] = *(const short8*)&lsA[cur][aRd + m * 512];
#pragma unroll
            for (int n = 0; n < NFR; ++n)
                bv[n] = *(const short8*)&lsB[cur][bRd + n * 512];
#pragma unroll
            for (int m = 0; m < MFR; ++m)
#pragma unroll
                for (int n = 0; n < NFR; ++n)
                    acc[m][n] = __builtin_amdgcn_mfma_f32_16x16x32_bf16(
                        av[m], bv[n], acc[m][n], 0, 0, 0);

            __syncthreads();
        }
    }

    // D: col(lane&15)=pixel, row=(lane>>4)*4+reg=cout-within-16
#pragma unroll
    for (int m = 0; m < MFR; ++m)
#pragma unroll
        for (int n = 0; n < NFR; ++n) {
            int cout = cb + wm * 16 * MFR + m * 16 + gq * 4;
            int pxl = wn * 16 * NFR + n * 16 + n15;
            int r = pxl / PC, c = pxl % PC;
            float* op = Y + ((size_t)(b * H + gy0 + r) * W + gx0 + c) * 256 + cout;
            *(f32x4*)op = acc[m][n];
        }
}

// ---- IDWT mid: ll (+llB) + hi (+hiB) -> out 64ch NHWC ----
template <int H2>
__global__ __launch_bounds__(256) void idwt_mid_kernel(
    const float* __restrict__ ll, const float* __restrict__ llB, int llStride,
    const float* __restrict__ hi, const float* __restrict__ hiB,
    float* __restrict__ out)
{
    constexpr int W2 = H2;
    const int c = threadIdx.x & 63;
    const int jj = threadIdx.x >> 6;
    const int j = blockIdx.x * 4 + jj;
    const int i = blockIdx.y;
    const int b = blockIdx.z;

    size_t pix = (size_t)(b * H2 + i) * W2 + j;
    float vll = ll[pix * llStride + c];
    if (llB) vll += llB[pix * llStride + c];
    const float* hp = hi + pix * 256;
    float vlh = hp[64 + c];
    float vhl = hp[128 + c];
    float vhh = hp[192 + c];
    if (hiB) {
        const float* hq = hiB + pix * 256;
        vlh += hq[64 + c];
        vhl += hq[128 + c];
        vhh += hq[192 + c];
    }
    float a  = vll + vlh + vhl + vhh;
    float b2 = vll + vlh - vhl - vhh;
    float c2 = vll - vlh + vhl - vhh;
    float d2 = vll - vlh - vhl + vhh;
    float* op = out + ((size_t)(b * 2 * H2 + 2 * i) * (2 * W2) + 2 * j) * 64 + c;
    op[0] = a;
    op[64] = b2;
    op[(size_t)(2 * W2) * 64] = c2;
    op[(size_t)(2 * W2) * 64 + 64] = d2;
}

// ---- final IDWT: ll0u [4][96][96][64] + y0 (+y0b) highs + bias -> NCHW ----
__global__ __launch_bounds__(256) void idwt_final_kernel(
    const float* __restrict__ ll, const float* __restrict__ hi,
    const float* __restrict__ hiB,
    const float* __restrict__ bias, float* __restrict__ out)
{
    __shared__ float lds[16 * 324];
    const int tt = blockIdx.x;               // 12x12 tiles
    const int tyi = tt / 12, txi = tt % 12;
    const int y0 = tyi * 8, x0 = txi * 8;
    const int cg = blockIdx.y;               // 0..3
    const int b = blockIdx.z;
    const int tid = threadIdx.x;

#pragma unroll
    for (int rep = 0; rep < 4; ++rep) {
        int idx = rep * 256 + tid;
        int c16 = idx & 15;
        int px = idx >> 4;                   // 0..63
        int pi = px >> 3, pj = px & 7;
        int c = cg * 16 + c16;
        size_t pix = (size_t)(b * 96 + y0 + pi) * 96 + x0 + pj;
        float vll = ll[pix * 64 + c];
        const float* hp = hi + pix * 256;
        float vlh = hp[64 + c];
        float vhl = hp[128 + c];
        float vhh = hp[192 + c];
        if (hiB) {
            const float* hq = hiB + pix * 256;
            vlh += hq[64 + c];
            vhl += hq[128 + c];
            vhh += hq[192 + c];
        }
        float bv = bias[c];
        float a  = vll + vlh + vhl + vhh + bv;
        float b2 = vll + vlh - vhl - vhh + bv;
        float c2 = vll - vlh + vhl - vhh + bv;
        float d2 = vll - vlh - vhl + vhh + bv;
        float* l = lds + c16 * 324 + (2 * pi) * 20 + 2 * pj;
        l[0] = a; l[1] = b2;
        l[20] = c2; l[21] = d2;
    }
    __syncthreads();

    const int c16 = tid >> 4;
    const int yy = tid & 15;
    const float* l = lds + c16 * 324 + yy * 20;
    float* op = out + ((size_t)(b * 64 + cg * 16 + c16) * 192 + tyi * 16 + yy) * 192 + txi * 16;
#pragma unroll
    for (int q = 0; q < 4; ++q)
        *(f32x4*)(op + 4 * q) = *(const f32x4*)(l + 4 * q);
}

extern "C" void kernel_launch(void* const* d_in, const int* in_sizes, int n_in,
                              void* d_out, int out_size, void* d_ws, size_t ws_size,
                              hipStream_t stream)
{
    const float* x    = (const float*)d_in[0];
    const float* w0   = (const float*)d_in[1];
    const float* w1   = (const float*)d_in[2];
    const float* w2   = (const float*)d_in[3];
    const float* bias = (const float*)d_in[4];
    float* out = (float*)d_out;

    char* ws = (char*)d_ws;
    unsigned short* wT0 = (unsigned short*)(ws + 0);          // 1,179,648 B
    unsigned short* wT1 = (unsigned short*)(ws + 1179648);
    unsigned short* wT2 = (unsigned short*)(ws + 2359296);
    unsigned short* Xp0 = (unsigned short*)(ws + 3538944);    // 19,668,992 B
    unsigned short* Xp1 = (unsigned short*)(ws + 23207936);   //  5,120,000 B
    unsigned short* Xp2 = (unsigned short*)(ws + 28327936);   //  1,384,448 B
    float* y0 = (float*)(ws + 29712384);                      // 37,748,736 B
    float* y1 = (float*)(ws + 67461120);                      //  9,437,184 B
    float* y2 = (float*)(ws + 76898304);                      //  2,359,296 B
    // K-split partial buffers (needs ws_size >= 128,802,816)
    float* y0b = (float*)(ws + 79257600);                     // 37,748,736 B
    float* y1b = (float*)(ws + 117006336);                    //  9,437,184 B
    float* y2b = (float*)(ws + 126443520);                    //  2,359,296 B
    float* ll1u = (float*)Xp1;   // alias: Xp1 dead after conv1
    float* ll0u = (float*)Xp0;   // alias: Xp0 dead after conv0

    const bool split = ws_size >= 128802816ull;
    float* p0 = split ? y0b : nullptr;
    float* p1 = split ? y1b : nullptr;
    float* p2 = split ? y2b : nullptr;

    border_zero_kernel<<<342, 256, 0, stream>>>(Xp0, Xp1, Xp2);
    prep_w_kernel<<<dim3(288, 3), 256, 0, stream>>>(w0, w1, w2, wT0, wT1, wT2);

    dwt0_kernel<<<dim3(6, 96, 4), 256, 0, stream>>>(x, Xp0);
    if (split)
        conv_lds_kernel<98, 98, 128, 8, 16, 2, 2, 36, 2>
            <<<dim3(288, 2, 2), 256, 0, stream>>>((const short*)Xp0, (const short*)wT0, y0, y0b);
    else
        conv_lds_kernel<98, 98, 128, 8, 16, 2, 2, 36, 1>
            <<<dim3(288, 2, 1), 256, 0, stream>>>((const short*)Xp0, (const short*)wT0, y0, y0);

    dwt_mid_kernel<48, 16><<<dim3(3, 48, 4), 256, 0, stream>>>(y0, p0, Xp1);
    if (split)
        conv_lds_kernel<50, 50, 128, 8, 16, 2, 2, 9, 2>
            <<<dim3(72, 2, 2), 256, 0, stream>>>((const short*)Xp1, (const short*)wT1, y1, y1b);
    else
        conv_lds_kernel<50, 50, 128, 8, 16, 2, 2, 9, 1>
            <<<dim3(72, 2, 1), 256, 0, stream>>>((const short*)Xp1, (const short*)wT1, y1, y1);

    dwt_mid_kernel<24, 12><<<dim3(2, 24, 4), 256, 0, stream>>>(y1, p1, Xp2);
    if (split)
        conv_lds_kernel<26, 26, 128, 8, 8, 2, 2, 0, 2>
            <<<dim3(36, 2, 2), 256, 0, stream>>>((const short*)Xp2, (const short*)wT2, y2, y2b);
    else
        conv_lds_kernel<26, 26, 128, 8, 8, 2, 2, 0, 1>
            <<<dim3(36, 2, 1), 256, 0, stream>>>((const short*)Xp2, (const short*)wT2, y2, y2);

    idwt_mid_kernel<24><<<dim3(6, 24, 4), 256, 0, stream>>>(y2, p2, 256, y2, p2, ll1u);
    idwt_mid_kernel<48><<<dim3(12, 48, 4), 256, 0, stream>>>(ll1u, nullptr, 64, y1, p1, ll0u);
    idwt_final_kernel<<<dim3(144, 4, 4), 256, 0, stream>>>(ll0u, y0, p0, bias, out);
}